// Round 4
// baseline (916.233 us; speedup 1.0000x reference)
//
#include <hip/hip_runtime.h>
#include <hip/hip_bf16.h>

// Problem constants
#define HN 12
#define DHD 64
#define BB 128
#define SQ 197
#define DD 768
#define TOK (BB*SQ)      // 25216 = 64*394
#define SP 224           // padded S for MFMA
#define SPS 232          // LDS stride in shorts (464B, 16B-aligned)

using short8  = __attribute__((ext_vector_type(8))) short;
using floatx4 = __attribute__((ext_vector_type(4))) float;

__device__ __forceinline__ float bf2f(short v) {
    union { unsigned int u; float f; } x;
    x.u = ((unsigned int)(unsigned short)v) << 16;
    return x.f;
}
__device__ __forceinline__ short f2bf(float f) {
    union { float f; unsigned int u; } x; x.f = f;
    unsigned int u = x.u;
    u += 0x7fffu + ((u >> 16) & 1u);   // RNE
    return (short)(u >> 16);
}
__device__ __forceinline__ float ldf(const void* p, size_t i, bool isf32) {
    return isf32 ? ((const float*)p)[i] : bf2f(((const short*)p)[i]);
}

// ---------------------------------------------------------------------------
// Dtype detection: even-index shorts of Wq. bf16 weights have exponents
// ~110..125; f32 low-mantissa halves are ~uniform -> ~50% extreme.
// ---------------------------------------------------------------------------
__global__ __launch_bounds__(256) void detect_kernel(
        const short* __restrict__ wq, float* __restrict__ flag) {
    __shared__ int cnt;
    if (threadIdx.x == 0) cnt = 0;
    __syncthreads();
    int local = 0;
    for (int j = 0; j < 16; j++) {
        int i = threadIdx.x * 16 + j;            // 4096 samples, bytes < 16.4KB
        unsigned int u = (unsigned short)wq[2 * i];
        unsigned int e = (u >> 7) & 0xFF;
        if (e < 64 || e >= 192) local++;
    }
    for (int d = 1; d < 64; d <<= 1) local += __shfl_xor(local, d, 64);
    if ((threadIdx.x & 63) == 0) atomicAdd(&cnt, local);
    __syncthreads();
    if (threadIdx.x == 0) *flag = (cnt > 256) ? 1.f : 0.f;
}

__global__ void sentinel_kernel(short* out, int n, float code) {
    int i = blockIdx.x * 256 + threadIdx.x;
    if (i < n) out[i] = (i == 0) ? f2bf(code) : (short)0;
}

// ---------------------------------------------------------------------------
// Scoring MLP -> mask.  One wave per token.
// ---------------------------------------------------------------------------
__global__ __launch_bounds__(256) void mask_kernel(
        const void* __restrict__ hs, const void* __restrict__ W1,
        const void* __restrict__ b1, const void* __restrict__ W2,
        const void* __restrict__ b2, float* __restrict__ mask,
        const float* __restrict__ flag) {
    __shared__ float hrow[4][DD];
    bool isf32 = (*flag != 0.f);
    int tid = threadIdx.x, lane = tid & 63, wave = tid >> 6;
    int token = blockIdx.x * 4 + wave;          // TOK == 6304*4 exactly
    for (int i = lane; i < DD; i += 64)
        hrow[wave][i] = ldf(hs, (size_t)token * DD + i, isf32);
    __syncthreads();
    int s = token % SQ;
    float m = 1.f;
    if (s != 0) {
        float acc = ldf(b1, lane, isf32);
        #pragma unroll 8
        for (int k = 0; k < DD; k++)
            acc = fmaf(hrow[wave][k], ldf(W1, k * 64 + lane, isf32), acc);
        float hv = fmaxf(acc, 0.f);
        float o  = hv * ldf(W2, lane, isf32);
        for (int d = 1; d < 64; d <<= 1) o += __shfl_xor(o, d, 64);
        float logit = o + ldf(b2, 0, isf32);
        float sg = 1.f / (1.f + __expf(-logit));
        m = (sg >= 0.05f) ? 1.f : 0.f;
    }
    if (lane == 0) mask[token] = m;
}

// ---------------------------------------------------------------------------
// GEMM  C[rows m0g+m][N] = A[m0g+m][K] * B[K][N] + bias (+ masked epilogue).
// B = up-to-3 weights, each [K][768] natural layout; n-tile selects one.
// m0g = global row offset (chunking), Mreal = rows in this chunk.
// MODE 0: A external dual-dtype, C internal bf16 (QKV).
// MODE 1: A internal bf16 (ctx), C external dual-dtype (d_out).
// ---------------------------------------------------------------------------
template <int MODE>
__global__ __launch_bounds__(256) void gemm_bn(
        const void* __restrict__ A, const void* __restrict__ B0,
        const void* __restrict__ B1, const void* __restrict__ B2,
        const void* __restrict__ bias0, const void* __restrict__ bias1,
        const void* __restrict__ bias2, void* __restrict__ C,
        int m0g, int Mreal, int N, int K,
        const float* __restrict__ mask, const short* __restrict__ resid,
        const void* __restrict__ hs, const float* __restrict__ flag) {
    constexpr int LDA = 40;
    constexpr int LDB = 68;
    __shared__ __align__(16) short As[64 * LDA];
    __shared__ __align__(16) short Bs[32 * LDB];
    bool isf32 = (*flag != 0.f);
    int tiles_n = N / 64;
    int bn = blockIdx.x % tiles_n, bm = blockIdx.x / tiles_n;
    int m0 = bm * 64, n0 = bn * 64;
    int grp = n0 / DD, coln0 = n0 - grp * DD;
    const void* Bp  = (grp == 0) ? B0    : (grp == 1) ? B1    : B2;
    const void* bip = (grp == 0) ? bias0 : (grp == 1) ? bias1 : bias2;
    int tid = threadIdx.x, lane = tid & 63, wave = tid >> 6;
    int wx = wave & 1, wy = wave >> 1;
    int quad = lane >> 4, l16 = lane & 15;
    int arow = tid >> 2, akk = (tid & 3) * 8;
    int brow = tid >> 3, bnn = (tid & 7) * 8;
    int ar = m0 + arow; if (ar >= Mreal) ar = Mreal - 1;
    size_t arg = (size_t)(MODE == 0 ? m0g + ar : ar);   // A row (global/local)

    floatx4 acc[2][2] = {};
    for (int k0 = 0; k0 < K; k0 += 32) {
        if (MODE == 0 && isf32) {
            const float* Af = (const float*)A;
            float4 f0 = *(const float4*)&Af[arg * K + k0 + akk];
            float4 f1 = *(const float4*)&Af[arg * K + k0 + akk + 4];
            short8 s;
            s[0]=f2bf(f0.x); s[1]=f2bf(f0.y); s[2]=f2bf(f0.z); s[3]=f2bf(f0.w);
            s[4]=f2bf(f1.x); s[5]=f2bf(f1.y); s[6]=f2bf(f1.z); s[7]=f2bf(f1.w);
            *(short8*)&As[arow * LDA + akk] = s;
        } else {
            *(float4*)&As[arow * LDA + akk] =
                *(const float4*)&((const short*)A)[arg * K + k0 + akk];
        }
        {
            size_t bo = (size_t)(k0 + brow) * DD + coln0 + bnn;
            if (isf32) {
                const float* Bf = (const float*)Bp;
                float4 f0 = *(const float4*)&Bf[bo];
                float4 f1 = *(const float4*)&Bf[bo + 4];
                short8 s;
                s[0]=f2bf(f0.x); s[1]=f2bf(f0.y); s[2]=f2bf(f0.z); s[3]=f2bf(f0.w);
                s[4]=f2bf(f1.x); s[5]=f2bf(f1.y); s[6]=f2bf(f1.z); s[7]=f2bf(f1.w);
                *(short8*)&Bs[brow * LDB + bnn] = s;
            } else {
                *(float4*)&Bs[brow * LDB + bnn] =
                    *(const float4*)&((const short*)Bp)[bo];
            }
        }
        __syncthreads();
        short8 a0 = *(const short8*)&As[(wy*32 + l16) * LDA + quad*8];
        short8 a1 = *(const short8*)&As[(wy*32 + 16 + l16) * LDA + quad*8];
        short8 b0, b1;
        #pragma unroll
        for (int j = 0; j < 8; j++) {
            int krow = quad * 8 + j;
            b0[j] = Bs[krow * LDB + wx*32 + l16];
            b1[j] = Bs[krow * LDB + wx*32 + 16 + l16];
        }
        acc[0][0] = __builtin_amdgcn_mfma_f32_16x16x32_bf16(a0, b0, acc[0][0], 0, 0, 0);
        acc[0][1] = __builtin_amdgcn_mfma_f32_16x16x32_bf16(a0, b1, acc[0][1], 0, 0, 0);
        acc[1][0] = __builtin_amdgcn_mfma_f32_16x16x32_bf16(a1, b0, acc[1][0], 0, 0, 0);
        acc[1][1] = __builtin_amdgcn_mfma_f32_16x16x32_bf16(a1, b1, acc[1][1], 0, 0, 0);
        __syncthreads();
    }
    for (int i = 0; i < 2; i++)
        for (int j = 0; j < 2; j++) {
            int n  = n0 + wx * 32 + j * 16 + l16;
            int nn = coln0 + wx * 32 + j * 16 + l16;
            float bb = ldf(bip, nn, isf32);
            for (int r = 0; r < 4; r++) {
                int m = m0 + wy * 32 + i * 16 + quad * 4 + r;
                if (m >= Mreal) continue;
                float v = acc[i][j][r] + bb;
                if (MODE == 0) {
                    ((short*)C)[(size_t)m * N + n] = f2bf(v);
                } else {
                    size_t gm = (size_t)(m0g + m);
                    v += bf2f(resid[(size_t)m * N + n]);
                    if (mask[gm] == 0.f) v = ldf(hs, gm * N + n, isf32);
                    if (isf32) ((float*)C)[gm * N + n] = v;
                    else       ((short*)C)[gm * N + n] = f2bf(v);
                }
            }
        }
}

// ---------------------------------------------------------------------------
// Attention: block = (b, h, 64 q-rows); wave = 16 q-rows. Internal bf16.
// ---------------------------------------------------------------------------
__global__ __launch_bounds__(256) void attn_kernel(
        const short* __restrict__ qkv, short* __restrict__ ctx) {
    __shared__ __align__(16) short Vt[DHD * SPS];
    __shared__ __align__(16) short P[4 * 16 * SPS];
    int blk = blockIdx.x;
    int qc = blk & 3;
    int h  = (blk >> 2) % HN;
    int b  = blk / (4 * HN);
    int tid = threadIdx.x, lane = tid & 63, wave = tid >> 6;
    int quad = lane >> 4, l16 = lane & 15;
    const short* base = qkv + (size_t)b * SQ * 2304;

    for (int i = tid; i < SQ * DHD; i += 256) {
        int s = i >> 6, d = i & 63;
        Vt[d * SPS + s] = base[(size_t)s * 2304 + 1536 + h * 64 + d];
    }
    for (int i = tid; i < (SP - SQ) * DHD; i += 256) {
        int s = SQ + i % (SP - SQ), d = i / (SP - SQ);
        Vt[d * SPS + s] = 0;
    }
    __syncthreads();

    int mrow = qc * 64 + wave * 16 + l16;
    if (mrow > SQ - 1) mrow = SQ - 1;
    const short* Qrow = base + (size_t)mrow * 2304 + h * 64;
    short8 aq0 = *(const short8*)(Qrow + quad * 8);
    short8 aq1 = *(const short8*)(Qrow + 32 + quad * 8);

    floatx4 sc[14];
    for (int t = 0; t < 14; t++) {
        int nrow = t * 16 + l16;
        if (nrow > SQ - 1) nrow = SQ - 1;
        const short* Krow = base + (size_t)nrow * 2304 + DD + h * 64;
        short8 b0 = *(const short8*)(Krow + quad * 8);
        short8 b1 = *(const short8*)(Krow + 32 + quad * 8);
        floatx4 c = {0.f, 0.f, 0.f, 0.f};
        c = __builtin_amdgcn_mfma_f32_16x16x32_bf16(aq0, b0, c, 0, 0, 0);
        c = __builtin_amdgcn_mfma_f32_16x16x32_bf16(aq1, b1, c, 0, 0, 0);
        sc[t] = c;
    }

    const float scale = 0.125f;
    float mx[4] = {-1e30f, -1e30f, -1e30f, -1e30f};
    for (int t = 0; t < 14; t++) {
        int col = t * 16 + l16;
        if (col < SQ)
            for (int r = 0; r < 4; r++) mx[r] = fmaxf(mx[r], sc[t][r]);
    }
    for (int d = 1; d < 16; d <<= 1)
        for (int r = 0; r < 4; r++) mx[r] = fmaxf(mx[r], __shfl_xor(mx[r], d, 64));
    float sum[4] = {0.f, 0.f, 0.f, 0.f};
    for (int t = 0; t < 14; t++) {
        int col = t * 16 + l16;
        for (int r = 0; r < 4; r++) {
            float e = (col < SQ) ? __expf((sc[t][r] - mx[r]) * scale) : 0.f;
            sc[t][r] = e; sum[r] += e;
        }
    }
    for (int d = 1; d < 16; d <<= 1)
        for (int r = 0; r < 4; r++) sum[r] += __shfl_xor(sum[r], d, 64);
    float inv[4];
    for (int r = 0; r < 4; r++) inv[r] = 1.f / sum[r];

    short* Pw = &P[wave * 16 * SPS];
    for (int t = 0; t < 14; t++)
        for (int r = 0; r < 4; r++)
            Pw[(quad * 4 + r) * SPS + t * 16 + l16] = f2bf(sc[t][r] * inv[r]);
    __syncthreads();

    floatx4 co[4] = {};
    for (int ks = 0; ks < 7; ks++) {
        short8 pa = *(const short8*)&Pw[l16 * SPS + ks * 32 + quad * 8];
        for (int j = 0; j < 4; j++) {
            short8 vb = *(const short8*)&Vt[(j * 16 + l16) * SPS + ks * 32 + quad * 8];
            co[j] = __builtin_amdgcn_mfma_f32_16x16x32_bf16(pa, vb, co[j], 0, 0, 0);
        }
    }
    int sq0 = qc * 64 + wave * 16 + quad * 4;
    for (int r = 0; r < 4; r++) {
        int s = sq0 + r;
        if (s < SQ) {
            size_t o = ((size_t)(b * SQ + s)) * DD + h * 64;
            for (int j = 0; j < 4; j++)
                ctx[o + j * 16 + l16] = f2bf(co[j][r]);
        }
    }
}

// ---------------------------------------------------------------------------
extern "C" void kernel_launch(void* const* d_in, const int* in_sizes, int n_in,
                              void* d_out, int out_size, void* d_ws, size_t ws_size,
                              hipStream_t stream) {
    const void* hs = d_in[0];
    const void* Wq = d_in[1];
    const void* bq = d_in[2];
    const void* Wk = d_in[3];
    const void* bk = d_in[4];
    const void* Wv = d_in[5];
    const void* bv = d_in[6];
    const void* Wd = d_in[7];
    const void* bd = d_in[8];
    const void* W1 = d_in[9];
    const void* b1 = d_in[10];
    const void* W2 = d_in[11];
    const void* b2 = d_in[12];

    const size_t flag_b = 16;
    const size_t mask_b = (size_t)TOK * 4;

    int CHB = 0;
    for (int c = 128; c >= 1; c >>= 1) {
        size_t chtp = (size_t)((c * SQ + 63) / 64) * 64;
        size_t need = flag_b + mask_b + chtp * 2304 * 2 + chtp * DD * 2;
        if (need <= ws_size) { CHB = c; break; }
    }
    if (CHB == 0) {
        sentinel_kernel<<<(out_size + 255) / 256, 256, 0, stream>>>(
            (short*)d_out, out_size, (float)((double)ws_size / 1.0e6));
        return;
    }
    const int CHT  = CHB * SQ;
    const int CHTP = ((CHT + 63) / 64) * 64;

    char* ws = (char*)d_ws;
    float* flag = (float*)ws;
    float* mask = (float*)(ws + flag_b);
    short* QKVc = (short*)(ws + flag_b + mask_b);
    short* ctxc = QKVc + (size_t)CHTP * 2304;

    detect_kernel<<<1, 256, 0, stream>>>((const short*)Wq, flag);
    mask_kernel<<<TOK / 4, 256, 0, stream>>>(hs, W1, b1, W2, b2, mask, flag);

    const int nchunk = BB / CHB;
    for (int c = 0; c < nchunk; c++) {
        const int m0g = c * CHT;
        gemm_bn<0><<<(CHTP / 64) * (3 * DD / 64), 256, 0, stream>>>(
            hs, Wq, Wk, Wv, bq, bk, bv, QKVc,
            m0g, CHT, 3 * DD, DD, nullptr, nullptr, nullptr, flag);
        attn_kernel<<<CHB * HN * 4, 256, 0, stream>>>(QKVc, ctxc);
        gemm_bn<1><<<(CHTP / 64) * (DD / 64), 256, 0, stream>>>(
            ctxc, Wd, nullptr, nullptr, bd, nullptr, nullptr, d_out,
            m0g, CHT, DD, DD, mask, ctxc, hs, flag);
    }
}